// Round 13
// baseline (103.848 us; speedup 1.0000x reference)
//
#include <hip/hip_runtime.h>
#include <hip/hip_bf16.h>

#define NN 16384
#define DD 128
#define TS 64                  // strip height == tile size (64x64 tiles)
#define NS 256                 // number of strips
#define NTILES 32896           // NS*(NS+1)/2 triangular tiles
#define SQRT_SCALE 4.5398159622f   // sqrt(log2(e)/0.07); dot of scaled vecs == exp2 arg

// Schraudolph exp2: exp2(y) ~= bitcast<f32>((int)(y*2^23 + (127*2^23 - C)))
#define EXP_A 8388608.0f       // 2^23
#define EXP_K 1064986316.0f    // 127*2^23 - C, C=366585 (min max-rel-err +-3%)

typedef __attribute__((ext_vector_type(8))) short bf16x8;
typedef __attribute__((ext_vector_type(4))) float f32x4;

// T(s) = number of triangular tiles before strip s
#define TRI(s) (256 * (s) - ((s) * ((s)-1)) / 2)

// ---------------- Kernel 1: fp32 -> scaled bf16, swizzled layout ---------------
// 16B chunk c of row r stored at chunk position (c ^ (r&15)).
__global__ void convert_swz(const float* __restrict__ x, ushort* __restrict__ xb) {
    int t = blockIdx.x * blockDim.x + threadIdx.x;   // one thread per 8-elem chunk
    int r = t >> 4;
    int c = t & 15;
    const float4* src = (const float4*)(x + (size_t)r * DD + c * 8);
    float4 f0 = src[0];
    float4 f1 = src[1];
    float vals[8] = {f0.x, f0.y, f0.z, f0.w, f1.x, f1.y, f1.z, f1.w};
    bf16x8 v;
#pragma unroll
    for (int i = 0; i < 8; ++i) {
        __hip_bfloat16 h = __float2bfloat16(vals[i] * SQRT_SCALE);
        v[i] = (short)__builtin_bit_cast(unsigned short, h);
    }
    int cs = c ^ (r & 15);
    *(bf16x8*)(xb + (size_t)r * DD + cs * 8) = v;
}

// ---------------- Kernel 2: triangular X·X^T -> exp2 -> sums, one strip/block --
// Grid 4096 = 256 strips x 16 chunks. Block (s,c) computes tiles
// ct in [s + c*(256-s)/16, s + (c+1)*(256-s)/16) of strip s: branch-free inner
// loop, af loaded once, rows flushed once. B frags reg-direct (dbuf bA/bB),
// no LDS, no barriers. Per-lane col partials -> bf16 rank scratch (no atomics).
__global__ __launch_bounds__(256, 3) void gemm_exp_tri(const ushort* __restrict__ xb,
                                                       float* __restrict__ rowsum,
                                                       ushort* __restrict__ colscr) {
    const int tid  = threadIdx.x;
    const int lane = tid & 63;
    const int cw   = tid >> 6;       // 0..3 colwave
    const int frow = lane & 15;
    const int kq   = lane >> 4;

    const int bidx = blockIdx.x;     // s*16 + c ; s=0 (largest work) first
    const int s   = bidx >> 4;
    const int c   = bidx & 15;
    const int n_s = NS - s;
    const int ct0 = s + ((c * n_s) >> 4);
    const int ct1 = s + (((c + 1) * n_s) >> 4);
    const int nt  = ct1 - ct0;
    if (nt == 0) return;

    // ---- per-lane swizzled chunk offsets (row&15 == frow) ----
    int slot[4];
#pragma unroll
    for (int kk = 0; kk < 4; ++kk)
        slot[kk] = ((((kk << 2) | kq) ^ frow) << 3);

    const ushort* bbase = xb + (size_t)(cw * 16 + frow) * DD;
    auto bload = [&](bf16x8 (&buf)[4], int ct) {
        const ushort* p = bbase + (size_t)ct * (TS * DD);
#pragma unroll
        for (int kk = 0; kk < 4; ++kk)
            buf[kk] = *(const bf16x8*)(p + slot[kk]);
    };

    bf16x8 bA[4], bB[4];
    bload(bA, ct0);
    if (nt > 1) bload(bB, ct0 + 1);

    // ---- A fragments for strip s: 64 rows, K=128, loaded ONCE ----
    bf16x8 af[4][4];
#pragma unroll
    for (int m = 0; m < 4; ++m) {
        const ushort* p = xb + (size_t)(s * TS + m * 16 + frow) * DD;
#pragma unroll
        for (int kk = 0; kk < 4; ++kk)
            af[m][kk] = *(const bf16x8*)(p + slot[kk]);
    }

    const f32x4 zacc = {0.f, 0.f, 0.f, 0.f};
    float rs[4][4] = {};
    size_t colidx = (size_t)(TRI(s) + (ct0 - s)) * 256 + (cw << 6) + lane;

    auto body = [&](bf16x8 (&buf)[4], int q) {
        f32x4 acc[4];
        __builtin_amdgcn_s_setprio(1);
#pragma unroll
        for (int kk = 0; kk < 4; ++kk) {
            if (kk == 0) {
#pragma unroll
                for (int m = 0; m < 4; ++m)
                    acc[m] = __builtin_amdgcn_mfma_f32_16x16x32_bf16(
                        af[m][0], buf[0], zacc, 0, 0, 0);
            } else {
#pragma unroll
                for (int m = 0; m < 4; ++m)
                    acc[m] = __builtin_amdgcn_mfma_f32_16x16x32_bf16(
                        af[m][kk], buf[kk], acc[m], 0, 0, 0);
            }
        }
        __builtin_amdgcn_s_setprio(0);

        // MFMA issue consumed buf: refill with tile q+2 (WAR enforced by deps).
        if (q + 2 < nt) bload(buf, ct0 + q + 2);

        // ---- epilogue: Schraudolph exp2 + register row sums + lane col partial
        float cs = 0.f;
#pragma unroll
        for (int m = 0; m < 4; ++m)
#pragma unroll
            for (int j = 0; j < 4; ++j) {
                float b = __builtin_fmaf(acc[m][j], EXP_A, EXP_K);
                float e = __builtin_bit_cast(float, (int)b);
                rs[m][j] += e;
                cs += e;
            }
        // per-lane 16-row col partial -> bf16 scratch (diagonal tile stores 0:
        // its columns are fully counted by the row path)
        ushort v = (ct0 + q == s) ? (ushort)0
                 : __builtin_bit_cast(ushort, __float2bfloat16(cs));
        colscr[colidx + (size_t)q * 256] = v;
    };

    for (int q = 0; q < nt; q += 2) {
        body(bA, q);
        if (q + 1 < nt) body(bB, q + 1);
    }

    // ---- one row-sum flush per block: lane-reduce + atomicAdd ----
#pragma unroll
    for (int m = 0; m < 4; ++m)
#pragma unroll
        for (int j = 0; j < 4; ++j) {
            float v = rs[m][j];
            v += __shfl_xor(v, 1);
            v += __shfl_xor(v, 2);
            v += __shfl_xor(v, 4);
            v += __shfl_xor(v, 8);
            rs[m][j] = v;
        }
    if (frow == 0) {
#pragma unroll
        for (int m = 0; m < 4; ++m)
#pragma unroll
            for (int j = 0; j < 4; ++j)
                atomicAdd(&rowsum[s * TS + m * 16 + kq * 4 + j], rs[m][j]);
    }
}

// ---------------- Kernel 2b: column reduce + per-row log + block partial -------
// 128 blocks: block p owns columns of ct in {p, 255-p} (257 ranks, balanced).
// Thread e accumulates scratch entry e over the s-range; LDS merges the 4 kq
// entries per column; rows of those two strips are then FINAL -> log + reduce.
__global__ __launch_bounds__(256) void colfin(const ushort* __restrict__ colscr,
                                              const float* __restrict__ rowsum,
                                              float* __restrict__ partial) {
    const int p = blockIdx.x;        // 0..127
    const int e = threadIdx.x;       // 0..255
    const int ctA = p, ctB = 255 - p;

    float aA = 0.f, aB = 0.f;
#pragma unroll 4
    for (int s = 0; s <= ctA; ++s) {
        int rank = TRI(s) + (ctA - s);
        aA += __bfloat162float(__builtin_bit_cast(__hip_bfloat16,
                  colscr[(size_t)rank * 256 + e]));
    }
#pragma unroll 4
    for (int s = 0; s <= ctB; ++s) {
        int rank = TRI(s) + (ctB - s);
        aB += __bfloat162float(__builtin_bit_cast(__hip_bfloat16,
                  colscr[(size_t)rank * 256 + e]));
    }

    __shared__ float pA[256], pB[256];
    pA[e] = aA; pB[e] = aB;
    __syncthreads();

    float lsum = 0.f;
    if (e < 128) {
        const int half = e >> 6;     // 0 -> ctA, 1 -> ctB
        const int col  = e & 63;
        const int base = (col >> 4) * 64 + (col & 15);   // cw*64 + frow
        const float* P = half ? pB : pA;
        float csum = P[base] + P[base + 16] + P[base + 32] + P[base + 48];
        const int ct = half ? ctB : ctA;
        float r = rowsum[ct * TS + col] + csum;          // final row sum
        lsum = __builtin_amdgcn_logf(r) * 0.69314718056f;
    }
#pragma unroll
    for (int o = 1; o < 64; o <<= 1)
        lsum += __shfl_xor(lsum, o);
    __shared__ float ws[4];
    if ((e & 63) == 0) ws[e >> 6] = lsum;
    __syncthreads();
    if (e == 0)
        partial[p] = ws[0] + ws[1] + ws[2] + ws[3];
}

// ---------------- Kernel 3: final sum ------------------------------------------
__global__ void finalize_sum(const float* __restrict__ partial, float* __restrict__ out) {
    const int t = threadIdx.x;       // 64 threads
    float s = partial[t] + partial[t + 64];
#pragma unroll
    for (int o = 1; o < 64; o <<= 1)
        s += __shfl_xor(s, o);
    if (t == 0)
        out[0] = s * (1.0f / NN);
}

extern "C" void kernel_launch(void* const* d_in, const int* in_sizes, int n_in,
                              void* d_out, int out_size, void* d_ws, size_t ws_size,
                              hipStream_t stream) {
    const float* x = (const float*)d_in[0];
    float* out = (float*)d_out;

    ushort* xb      = (ushort*)d_ws;                                // 4 MB scaled bf16
    float* rowsum   = (float*)((char*)d_ws + (size_t)NN * DD * 2);  // 64 KB
    float* partial  = rowsum + NN;                                  // 512 B
    ushort* colscr  = (ushort*)(partial + 128);                     // 16.84 MB bf16

    hipMemsetAsync(rowsum, 0, NN * sizeof(float), stream);
    convert_swz<<<(NN * 16) / 256, 256, 0, stream>>>(x, xb);
    gemm_exp_tri<<<NS * 16, 256, 0, stream>>>(xb, rowsum, colscr);
    colfin<<<128, 256, 0, stream>>>(colscr, rowsum, partial);
    finalize_sum<<<1, 64, 0, stream>>>(partial, out);
}

// Round 14
// 96.464 us; speedup vs baseline: 1.0765x; 1.0765x over previous
//
#include <hip/hip_runtime.h>
#include <hip/hip_bf16.h>

#define NN 16384
#define DD 128
#define NSTRIP 128             // strips of 128 rows
#define NRANK 16512            // total 128x64 triangular tiles: sum(256-2s)
#define SQRT_SCALE 4.5398159622f   // sqrt(log2(e)/0.07); dot of scaled vecs == exp2 arg

// Schraudolph exp2: exp2(y) ~= bitcast<f32>((int)(y*2^23 + (127*2^23 - C)))
#define EXP_A 8388608.0f       // 2^23
#define EXP_K 1064986316.0f    // 127*2^23 - C, C=366585 (min max-rel-err +-3%)

typedef __attribute__((ext_vector_type(8))) short bf16x8;
typedef __attribute__((ext_vector_type(4))) float f32x4;

// rank(s,c) = s*(257-s) + (c - 2s), tiles ordered by strip then col-chunk
#define RANK0(s) ((s) * (257 - (s)))

// ---------------- Kernel 1: fp32 -> scaled bf16, swizzled layout ---------------
// 16B chunk c of row r stored at chunk position (c ^ (r&15)); linear global->LDS
// staging then yields bank-conflict-free ds_read_b128 fragment reads.
__global__ void convert_swz(const float* __restrict__ x, ushort* __restrict__ xb) {
    int t = blockIdx.x * blockDim.x + threadIdx.x;   // one thread per 8-elem chunk
    int r = t >> 4;
    int c = t & 15;
    const float4* src = (const float4*)(x + (size_t)r * DD + c * 8);
    float4 f0 = src[0];
    float4 f1 = src[1];
    float vals[8] = {f0.x, f0.y, f0.z, f0.w, f1.x, f1.y, f1.z, f1.w};
    bf16x8 v;
#pragma unroll
    for (int i = 0; i < 8; ++i) {
        __hip_bfloat16 h = __float2bfloat16(vals[i] * SQRT_SCALE);
        v[i] = (short)__builtin_bit_cast(unsigned short, h);
    }
    int cs = c ^ (r & 15);
    *(bf16x8*)(xb + (size_t)r * DD + cs * 8) = v;
}

// ---------------- Kernel 2: triangular X·X^T -> exp2 -> sums -------------------
// Tile = 128 rows x 64 cols. Block = 256 thr = 4 waves of 32 rows: af[2][4] +
// acc[2][4] keep VGPR ~115 -> 3 blocks/CU (12 waves). B tile (16 KB) staged
// ONCE per tile into LDS (global_load_lds, dbuf) and shared by all 4 waves ->
// 32-MFMA bursts per wave per tile and 2x less B traffic than 64-row blocks.
// Block (s,k) handles c = 2s+k, +16, ... (grid 128x16, big work first).
// Row sums in registers (one flush); col partials shfl-merged per wave and
// stored bf16 to rank scratch; c in {2s,2s+1} stores 0 (within-strip cells
// are fully covered by the two row paths -- exact partition).
__global__ __launch_bounds__(256, 3) void gemm_exp_tri(const ushort* __restrict__ xb,
                                                       float* __restrict__ rowsum,
                                                       ushort* __restrict__ colscr) {
    __shared__ __align__(16) ushort lB[2][64 * DD];   // 2 x 16 KB

    const int tid  = threadIdx.x;
    const int lane = tid & 63;
    const int wid  = tid >> 6;       // 0..3 (32-row slice)
    const int frow = lane & 15;
    const int kq   = lane >> 4;

    const int bid = blockIdx.x;
    const int s   = bid >> 4;        // strip
    const int k   = bid & 15;
    const int c0  = 2 * s + k;
    if (c0 > 255) return;
    const int nt  = ((255 - c0) >> 4) + 1;

    // ---- per-lane swizzled chunk offsets (xb row & 15 == frow for our rows) --
    int slot[4];
#pragma unroll
    for (int kk = 0; kk < 4; ++kk)
        slot[kk] = ((((kk << 2) | kq) ^ frow) << 3);       // ushort offset

    auto stage = [&](int buf, int c) {
        const char* g = (const char*)(xb + (size_t)c * 64 * DD);
#pragma unroll
        for (int i = 0; i < 4; ++i) {
            int off = (wid * 4 + i) * 1024;
            __builtin_amdgcn_global_load_lds(
                (const __attribute__((address_space(1))) unsigned int*)(g + off + lane * 16),
                (__attribute__((address_space(3))) unsigned int*)((char*)&lB[buf][0] + off),
                16, 0, 0);
        }
    };

    stage(0, c0);

    // ---- A fragments: this wave's 32 rows, K=128, in registers ----
    bf16x8 af[2][4];
#pragma unroll
    for (int m = 0; m < 2; ++m) {
        const ushort* p = xb + (size_t)(s * 128 + wid * 32 + m * 16 + frow) * DD;
#pragma unroll
        for (int kk = 0; kk < 4; ++kk)
            af[m][kk] = *(const bf16x8*)(p + slot[kk]);
    }

    // ---- LDS byte offsets for B fragments ----
    int nbase[4], kkoff[4];
#pragma unroll
    for (int n = 0; n < 4; ++n)
        nbase[n] = (n * 16 + frow) * 256;
#pragma unroll
    for (int kk = 0; kk < 4; ++kk)
        kkoff[kk] = slot[kk] * 2;

    asm volatile("s_waitcnt vmcnt(0)" ::: "memory");   // af + buf0 staged
    __builtin_amdgcn_s_barrier();

    const f32x4 zacc = {0.f, 0.f, 0.f, 0.f};
    float rs[2][4] = {};
    const int rank0 = RANK0(s) + k;

    for (int q = 0; q < nt; ++q) {
        const int cur = q & 1;
        if (q + 1 < nt) stage(cur ^ 1, c0 + 16 * (q + 1));

        const char* Bb = (const char*)&lB[cur][0];
        f32x4 acc[2][4];
        __builtin_amdgcn_s_setprio(1);
#pragma unroll
        for (int kk = 0; kk < 4; ++kk) {
            bf16x8 bfr[4];
#pragma unroll
            for (int n = 0; n < 4; ++n)
                bfr[n] = *(const bf16x8*)(Bb + nbase[n] + kkoff[kk]);
            if (kk == 0) {
#pragma unroll
                for (int m = 0; m < 2; ++m)
#pragma unroll
                    for (int n = 0; n < 4; ++n)
                        acc[m][n] = __builtin_amdgcn_mfma_f32_16x16x32_bf16(
                            af[m][0], bfr[n], zacc, 0, 0, 0);
            } else {
#pragma unroll
                for (int m = 0; m < 2; ++m)
#pragma unroll
                    for (int n = 0; n < 4; ++n)
                        acc[m][n] = __builtin_amdgcn_mfma_f32_16x16x32_bf16(
                            af[m][kk], bfr[n], acc[m][n], 0, 0, 0);
            }
        }
        __builtin_amdgcn_s_setprio(0);

        // ---- epilogue: Schraudolph exp2 + row sums (regs) + col partials ----
        float cs[4] = {0.f, 0.f, 0.f, 0.f};
#pragma unroll
        for (int m = 0; m < 2; ++m)
#pragma unroll
            for (int n = 0; n < 4; ++n)
#pragma unroll
                for (int j = 0; j < 4; ++j) {
                    float b = __builtin_fmaf(acc[m][n][j], EXP_A, EXP_K);
                    float e = __builtin_bit_cast(float, (int)b);
                    rs[m][j] += e;
                    cs[n] += e;
                }
        // merge the 4 kq row-groups -> full 32-row col sums; store per wave.
#pragma unroll
        for (int n = 0; n < 4; ++n) {
            float v = cs[n];
            v += __shfl_xor(v, 16);
            v += __shfl_xor(v, 32);
            cs[n] = v;
        }
        const bool diag = (q == 0) && (k < 2);     // c == 2s or 2s+1
        if (kq == 0) {
            const int rank = rank0 + 16 * q;
            size_t base = ((size_t)rank * 4 + wid) * 64 + frow;
#pragma unroll
            for (int n = 0; n < 4; ++n) {
                ushort v = diag ? (ushort)0
                         : __builtin_bit_cast(ushort, __float2bfloat16(cs[n]));
                colscr[base + n * 16] = v;
            }
        }

        asm volatile("s_waitcnt vmcnt(0)" ::: "memory");   // next buf + stores
        __builtin_amdgcn_s_barrier();
    }

    // ---- one row-sum flush: reduce over 16 col-lanes, atomicAdd ----
#pragma unroll
    for (int m = 0; m < 2; ++m)
#pragma unroll
        for (int j = 0; j < 4; ++j) {
            float v = rs[m][j];
            v += __shfl_xor(v, 1);
            v += __shfl_xor(v, 2);
            v += __shfl_xor(v, 4);
            v += __shfl_xor(v, 8);
            rs[m][j] = v;
        }
    if (frow == 0) {
#pragma unroll
        for (int m = 0; m < 2; ++m)
#pragma unroll
            for (int j = 0; j < 4; ++j)
                atomicAdd(&rowsum[s * 128 + wid * 32 + m * 16 + kq * 4 + j],
                          rs[m][j]);
    }
}

// ---------------- Kernel 2b: column reduce + log + per-chunk partial -----------
// Block c (0..255) owns global cols [64c, 64c+64) exclusively. Sums colscr over
// strips s <= c/2 (diag ranks hold 0), adds to rowsum, logs, reduces to
// partial[c]. Reads are 512B-coalesced per rank.
__global__ __launch_bounds__(256) void colfin(const ushort* __restrict__ colscr,
                                              const float* __restrict__ rowsum,
                                              float* __restrict__ partial) {
    const int c = blockIdx.x;
    const int t = threadIdx.x;
    const int e = t & 63;
    const int w = t >> 6;            // 0..3 (wave slot within rank record)
    const int smax = c >> 1;

    float a = 0.f;
    for (int s = 0; s <= smax; ++s) {
        int rank = RANK0(s) + (c - 2 * s);
        a += __bfloat162float(__builtin_bit_cast(__hip_bfloat16,
                 colscr[((size_t)rank * 4 + w) * 64 + e]));
    }
    __shared__ float p[4][64];
    p[w][e] = a;
    __syncthreads();

    float l = 0.f;
    if (t < 64) {
        float tot = p[0][t] + p[1][t] + p[2][t] + p[3][t];
        float r = rowsum[c * 64 + t] + tot;        // final row sum
        l = __builtin_amdgcn_logf(r) * 0.69314718056f;
    }
#pragma unroll
    for (int o = 1; o < 64; o <<= 1)
        l += __shfl_xor(l, o);
    if (t == 0)
        partial[c] = l;
}

// ---------------- Kernel 3: final sum ------------------------------------------
__global__ void finalize_sum(const float* __restrict__ partial, float* __restrict__ out) {
    const int t = threadIdx.x;       // 64 threads
    float s = (partial[t] + partial[t + 64]) + (partial[t + 128] + partial[t + 192]);
#pragma unroll
    for (int o = 1; o < 64; o <<= 1)
        s += __shfl_xor(s, o);
    if (t == 0)
        out[0] = s * (1.0f / NN);
}

extern "C" void kernel_launch(void* const* d_in, const int* in_sizes, int n_in,
                              void* d_out, int out_size, void* d_ws, size_t ws_size,
                              hipStream_t stream) {
    const float* x = (const float*)d_in[0];
    float* out = (float*)d_out;

    ushort* xb      = (ushort*)d_ws;                                // 4 MB scaled bf16
    float* rowsum   = (float*)((char*)d_ws + (size_t)NN * DD * 2);  // 64 KB
    float* partial  = rowsum + NN;                                  // 1 KB
    ushort* colscr  = (ushort*)(partial + 256);                     // 8.45 MB bf16

    hipMemsetAsync(rowsum, 0, NN * sizeof(float), stream);
    convert_swz<<<(NN * 16) / 256, 256, 0, stream>>>(x, xb);
    gemm_exp_tri<<<NSTRIP * 16, 256, 0, stream>>>(xb, rowsum, colscr);
    colfin<<<256, 256, 0, stream>>>(colscr, rowsum, partial);
    finalize_sum<<<1, 64, 0, stream>>>(partial, out);
}